// Round 9
// baseline (62.702 us; speedup 1.0000x reference)
//
#include <hip/hip_runtime.h>

#define CLS 64
#define DIM 256
#define NB  256          // main blocks (= partial slots); NB*WIN covers N
#define WIN 1024         // rows per block window (= threads)
#define MT  1024         // main threads
#define WPB 16           // waves per block
#define CPW 4            // classes per wave
#define P2  4            // reduce1 parts per class

typedef float f32x4 __attribute__((ext_vector_type(4)));

// ---- wave64 sum via DPP (VALU pipe); result uniform across all lanes ----
__device__ __forceinline__ float wave_sum64(float f) {
    int t;
    t = __builtin_amdgcn_update_dpp(0, __float_as_int(f), 0x111, 0xf, 0xf, false); f += __int_as_float(t); // row_shr:1
    t = __builtin_amdgcn_update_dpp(0, __float_as_int(f), 0x112, 0xf, 0xf, false); f += __int_as_float(t); // row_shr:2
    t = __builtin_amdgcn_update_dpp(0, __float_as_int(f), 0x114, 0xf, 0xe, false); f += __int_as_float(t); // row_shr:4
    t = __builtin_amdgcn_update_dpp(0, __float_as_int(f), 0x118, 0xf, 0xc, false); f += __int_as_float(t); // row_shr:8
    t = __builtin_amdgcn_update_dpp(0, __float_as_int(f), 0x142, 0xa, 0xf, false); f += __int_as_float(t); // row_bcast:15
    t = __builtin_amdgcn_update_dpp(0, __float_as_int(f), 0x143, 0xc, 0xf, false); f += __int_as_float(t); // row_bcast:31
    return __int_as_float(__builtin_amdgcn_readlane(__float_as_int(f), 63));
}

// ---- main: window-local bucket -> owner-wave gather -> register accumulate ----
__global__ __launch_bounds__(MT) void k_main(
    const float* __restrict__ emb, const int* __restrict__ labels, int N,
    float* __restrict__ partials,   // [CLS][NB][DIM]
    float* __restrict__ cnts)       // [CLS][NB]
{
    __shared__ unsigned short lst[WPB][WIN];   // 32 KB: entry = row(10b) | k(2b)<<10
    __shared__ int lcnt[WPB];

    const int tid  = threadIdx.x;
    const int w    = tid >> 6;                 // wave: owns classes 4w..4w+3
    const int lane = tid & 63;                 // lane l owns dims [4l, 4l+4)
    const int b    = blockIdx.x;

    f32x4 a0 = {0,0,0,0}, a1 = {0,0,0,0}, a2 = {0,0,0,0}, a3 = {0,0,0,0};
    float c0 = 0.f, c1 = 0.f, c2 = 0.f, c3 = 0.f;

    for (long long base = (long long)b * WIN; base < N; base += (long long)NB * WIN) {
        const int nrows = (int)min((long long)WIN, (long long)N - base);
        __syncthreads();                       // protect lst from prior window's walk
        if (tid < WPB) lcnt[tid] = 0;
        __syncthreads();
        if (tid < nrows) {                     // one-shot bucket by owner wave
            const int lab = labels[base + tid];
            const int g = lab >> 2;
            const int pos = atomicAdd(&lcnt[g], 1);
            lst[g][pos] = (unsigned short)(tid | ((lab & 3) << 10));
        }
        __syncthreads();

        const int n = lcnt[w];
        const float* embb = emb + (size_t)base * DIM;
        int j = 0;
        // 4 independent 1 KB row loads in flight per wave; wave-uniform scalar indices
        for (; j + 4 <= n; j += 4) {
            const unsigned long long e4 =
                *reinterpret_cast<const unsigned long long*>(&lst[w][j]);
            const int e0 = __builtin_amdgcn_readfirstlane((int)( e4        & 0xffff));
            const int e1 = __builtin_amdgcn_readfirstlane((int)((e4 >> 16) & 0xffff));
            const int e2 = __builtin_amdgcn_readfirstlane((int)((e4 >> 32) & 0xffff));
            const int e3 = __builtin_amdgcn_readfirstlane((int)((e4 >> 48) & 0xffff));
            const f32x4 v0 = *(reinterpret_cast<const f32x4*>(embb + (size_t)(e0 & 1023) * DIM) + lane);
            const f32x4 v1 = *(reinterpret_cast<const f32x4*>(embb + (size_t)(e1 & 1023) * DIM) + lane);
            const f32x4 v2 = *(reinterpret_cast<const f32x4*>(embb + (size_t)(e2 & 1023) * DIM) + lane);
            const f32x4 v3 = *(reinterpret_cast<const f32x4*>(embb + (size_t)(e3 & 1023) * DIM) + lane);
            const float s0 = wave_sum64(v0.x*v0.x + v0.y*v0.y + v0.z*v0.z + v0.w*v0.w);
            const float s1 = wave_sum64(v1.x*v1.x + v1.y*v1.y + v1.z*v1.z + v1.w*v1.w);
            const float s2 = wave_sum64(v2.x*v2.x + v2.y*v2.y + v2.z*v2.z + v2.w*v2.w);
            const float s3 = wave_sum64(v3.x*v3.x + v3.y*v3.y + v3.z*v3.z + v3.w*v3.w);
            const float i0 = 1.0f / fmaxf(sqrtf(s0), 1e-12f);
            const float i1 = 1.0f / fmaxf(sqrtf(s1), 1e-12f);
            const float i2 = 1.0f / fmaxf(sqrtf(s2), 1e-12f);
            const float i3 = 1.0f / fmaxf(sqrtf(s3), 1e-12f);
            {   f32x4 t; t.x = v0.x*i0; t.y = v0.y*i0; t.z = v0.z*i0; t.w = v0.w*i0;
                const int k = e0 >> 10;
                if      (k == 0) { a0 += t; c0 += 1.f; }
                else if (k == 1) { a1 += t; c1 += 1.f; }
                else if (k == 2) { a2 += t; c2 += 1.f; }
                else             { a3 += t; c3 += 1.f; } }
            {   f32x4 t; t.x = v1.x*i1; t.y = v1.y*i1; t.z = v1.z*i1; t.w = v1.w*i1;
                const int k = e1 >> 10;
                if      (k == 0) { a0 += t; c0 += 1.f; }
                else if (k == 1) { a1 += t; c1 += 1.f; }
                else if (k == 2) { a2 += t; c2 += 1.f; }
                else             { a3 += t; c3 += 1.f; } }
            {   f32x4 t; t.x = v2.x*i2; t.y = v2.y*i2; t.z = v2.z*i2; t.w = v2.w*i2;
                const int k = e2 >> 10;
                if      (k == 0) { a0 += t; c0 += 1.f; }
                else if (k == 1) { a1 += t; c1 += 1.f; }
                else if (k == 2) { a2 += t; c2 += 1.f; }
                else             { a3 += t; c3 += 1.f; } }
            {   f32x4 t; t.x = v3.x*i3; t.y = v3.y*i3; t.z = v3.z*i3; t.w = v3.w*i3;
                const int k = e3 >> 10;
                if      (k == 0) { a0 += t; c0 += 1.f; }
                else if (k == 1) { a1 += t; c1 += 1.f; }
                else if (k == 2) { a2 += t; c2 += 1.f; }
                else             { a3 += t; c3 += 1.f; } }
        }
        for (; j < n; ++j) {   // tail rows (< 4)
            const int e = __builtin_amdgcn_readfirstlane((int)lst[w][j]);
            const f32x4 v = *(reinterpret_cast<const f32x4*>(embb + (size_t)(e & 1023) * DIM) + lane);
            const float ss  = wave_sum64(v.x*v.x + v.y*v.y + v.z*v.z + v.w*v.w);
            const float inv = 1.0f / fmaxf(sqrtf(ss), 1e-12f);
            f32x4 t; t.x = v.x*inv; t.y = v.y*inv; t.z = v.z*inv; t.w = v.w*inv;
            const int k = e >> 10;
            if      (k == 0) { a0 += t; c0 += 1.f; }
            else if (k == 1) { a1 += t; c1 += 1.f; }
            else if (k == 2) { a2 += t; c2 += 1.f; }
            else             { a3 += t; c3 += 1.f; }
        }
    }

    // epilogue: coalesced 1 KB per-class stores + counts
    *reinterpret_cast<f32x4*>(partials + ((size_t)(w*CPW + 0) * NB + b) * DIM + 4*lane) = a0;
    *reinterpret_cast<f32x4*>(partials + ((size_t)(w*CPW + 1) * NB + b) * DIM + 4*lane) = a1;
    *reinterpret_cast<f32x4*>(partials + ((size_t)(w*CPW + 2) * NB + b) * DIM + 4*lane) = a2;
    *reinterpret_cast<f32x4*>(partials + ((size_t)(w*CPW + 3) * NB + b) * DIM + 4*lane) = a3;
    if (lane == 0) {
        cnts[(size_t)(w*CPW + 0) * NB + b] = c0;
        cnts[(size_t)(w*CPW + 1) * NB + b] = c1;
        cnts[(size_t)(w*CPW + 2) * NB + b] = c2;
        cnts[(size_t)(w*CPW + 3) * NB + b] = c3;
    }
}

// ---- reduce1: fold the NB block-partials to P2 chunks per class (coalesced) ----
__global__ __launch_bounds__(256) void k_reduce1(
    const float* __restrict__ partials, float* __restrict__ red1)
{
    const int c = blockIdx.x >> 2;             // / P2
    const int p = blockIdx.x & (P2 - 1);
    const int d = threadIdx.x;                 // 256 threads = one dim each
    const float* src = partials + ((size_t)c * NB + p * (NB / P2)) * DIM + d;
    float s = 0.f;
    #pragma unroll 8
    for (int bb = 0; bb < NB / P2; ++bb) s += src[(size_t)bb * DIM];
    red1[((size_t)c * P2 + p) * DIM + d] = s;
}

// ---- per-class loss ----
__global__ __launch_bounds__(256) void k_classloss(
    const float* __restrict__ red1, const float* __restrict__ cnts,
    float* __restrict__ closs, float* __restrict__ cvalid)
{
    const int c = blockIdx.x;   // 64 blocks
    const int d = threadIdx.x;  // 256 threads
    float s = 0.f;
    #pragma unroll
    for (int p = 0; p < P2; ++p) s += red1[((size_t)c * P2 + p) * DIM + d];
    const float w2 = wave_sum64(s * s);
    const float cw = wave_sum64(cnts[(size_t)c * NB + d]);   // NB==256 block-counts
    __shared__ float reds[4], redc[4];
    if ((d & 63) == 0) { reds[d >> 6] = w2; redc[d >> 6] = cw; }
    __syncthreads();
    if (d == 0) {
        float s2   = reds[0] + reds[1] + reds[2] + reds[3];  // ||sums_c||^2
        float cnt  = redc[0] + redc[1] + redc[2] + redc[3];
        float invc = 1.0f / fmaxf(cnt, 1.0f);
        float cn   = sqrtf(s2) * invc;                       // ||center_raw||
        float dot  = s2 * invc / fmaxf(cn, 1e-12f);          // sum over class of sim
        float pcs  = cnt - dot;                              // sum over class of (1 - sim)
        bool valid = cnt > 1.0f;
        closs[c]  = valid ? pcs * invc : 0.0f;
        cvalid[c] = valid ? 1.0f : 0.0f;
    }
}

// ---- final scalar ----
__global__ void k_final(const float* __restrict__ closs, const float* __restrict__ cvalid,
                        const int* __restrict__ epoch, float* __restrict__ out)
{
    const int t = threadIdx.x;  // 64
    const float sl = wave_sum64(closs[t]);
    const float nv = wave_sum64(cvalid[t]);
    if (t == 0) {
        float res = (nv > 0.0f) ? (sl / fmaxf(nv, 1.0f)) : 0.0f;
        if (epoch[0] < 1) res = 0.0f;   // START guard
        out[0] = res;
    }
}

extern "C" void kernel_launch(void* const* d_in, const int* in_sizes, int n_in,
                              void* d_out, int out_size, void* d_ws, size_t ws_size,
                              hipStream_t stream)
{
    const float* emb    = (const float*)d_in[0];
    const int*   labels = (const int*)d_in[1];
    const int*   epoch  = (const int*)d_in[2];
    float*       out    = (float*)d_out;
    const int N = in_sizes[0] / DIM;

    // workspace carve-up (all regions fully written before read, every call)
    char* ws = (char*)d_ws;
    size_t off = 0;
    auto carve = [&](size_t bytes) { size_t o = off; off = (off + bytes + 255) & ~(size_t)255; return o; };
    float* partials = (float*)(ws + carve((size_t)CLS * NB * DIM * sizeof(float)));  // 16 MB
    float* cnts     = (float*)(ws + carve((size_t)CLS * NB * sizeof(float)));        // 64 KB
    float* red1     = (float*)(ws + carve((size_t)CLS * P2 * DIM * sizeof(float)));  // 256 KB
    float* closs    = (float*)(ws + carve((size_t)CLS * sizeof(float)));
    float* cvalid   = (float*)(ws + carve((size_t)CLS * sizeof(float)));
    (void)ws_size;  // ~16.4 MB needed; harness provides ~1 GiB (observed via poison fill)

    k_main     <<<NB,       MT,  0, stream>>>(emb, labels, N, partials, cnts);
    k_reduce1  <<<CLS * P2, 256, 0, stream>>>(partials, red1);
    k_classloss<<<CLS,      256, 0, stream>>>(red1, cnts, closs, cvalid);
    k_final    <<<1,        64,  0, stream>>>(closs, cvalid, epoch, out);
}